// Round 18
// baseline (151.043 us; speedup 1.0000x reference)
//
#include <hip/hip_runtime.h>
#include <math.h>

#define DM 512
#define NS 64
#define LS 2048
#define NB 8
#define LF 4096
#define LSP (LS + (LS>>5))   // padded LDS length (kfft radix-8 engine only)

typedef float2 cf;
using bf16x8 = __attribute__((ext_vector_type(8))) short;
using f32x4  = __attribute__((ext_vector_type(4))) float;

__device__ __forceinline__ cf cmul(cf a, cf b){ return make_float2(a.x*b.x - a.y*b.y, a.x*b.y + a.y*b.x); }
__device__ __forceinline__ cf cadd(cf a, cf b){ return make_float2(a.x+b.x, a.y+b.y); }
__device__ __forceinline__ cf csub(cf a, cf b){ return make_float2(a.x-b.x, a.y-b.y); }
__device__ __forceinline__ cf cconjf(cf a){ return make_float2(a.x, -a.y); }
__device__ __forceinline__ cf cscalef(cf a, float s){ return make_float2(a.x*s, a.y*s); }
// approximate complex divide via v_rcp (plenty for 0.11 abs threshold)
__device__ __forceinline__ cf cdiv_fast(cf a, cf b){
  float inv = __builtin_amdgcn_rcpf(b.x*b.x + b.y*b.y);
  return make_float2((a.x*b.x + a.y*b.y)*inv, (a.y*b.x - a.x*b.y)*inv);
}

__device__ __forceinline__ float gelu_f(float x){
  return 0.5f*x*(1.0f + erff(x*0.7071067811865475f));
}

__device__ __forceinline__ ushort f2bf(float x){
  uint u = __float_as_uint(x);
  return (ushort)((u + 0x7fffu + ((u>>16)&1u)) >> 16);
}

// LDS pad helper (kfft radix-8 engine only)
__device__ __forceinline__ int lp(int x){ return x + (x >> 5); }

// float2 elementwise helpers
__device__ __forceinline__ float2 f2add(float2 a, float2 b){ return make_float2(a.x+b.x, a.y+b.y); }
__device__ __forceinline__ float2 f2mul(float2 a, float2 b){ return make_float2(a.x*b.x, a.y*b.y); }
__device__ __forceinline__ float2 f2fma(float2 a, float2 b, float2 c){
  return make_float2(fmaf(a.x,b.x,c.x), fmaf(a.y,b.y,c.y));
}
__device__ __forceinline__ float2 splat2(float s){ return make_float2(s,s); }
__device__ __forceinline__ float2 rcp2(float2 a){
  return make_float2(__builtin_amdgcn_rcpf(a.x), __builtin_amdgcn_rcpf(a.y));
}

// ---- Engine A (conv): N=2048, T=512 Stockham with LDS twiddle table.
// r17 split: stage m=1 done in REGISTERS (inputs i,i+512,i+1024,i+1536 are
// exactly each thread's 4 held values); stages m=4..256 in LDS; radix-2 tail
// (m=1024, twiddle=1) either in LDS (forward, natural order needed for the
// Hermitian mirror) or in REGISTERS (inverse, feeds pointwise epilogue).

// radix-4 butterfly on 4 register values + table twiddle, write 4 consecutive.
template<bool INV>
__device__ __forceinline__ void reg_stage1(cf c0, cf c1, cf c2, cf c3,
                                           const float2* tw, int tid, float2* dst)
{
  const float sg = INV ? 1.0f : -1.0f;
  float2 s02 = cadd(c0,c2), d02 = csub(c0,c2);
  float2 s13 = cadd(c1,c3), d13 = csub(c1,c3);
  float2 jd13 = make_float2(-sg*d13.y, sg*d13.x);
  float2 y0 = cadd(s02,s13);
  float2 y1 = cadd(d02,jd13);
  float2 y2 = csub(s02,s13);
  float2 y3 = csub(d02,jd13);
  float2 w1 = tw[tid];               // m=1 -> j=i=tid
  if (INV) w1.y = -w1.y;
  float2 w2 = cmul(w1,w1);
  float2 w3 = cmul(w2,w1);
  int o = 4*tid;
  dst[o]   = y0;
  dst[o+1] = cmul(y1,w1);
  dst[o+2] = cmul(y2,w2);
  dst[o+3] = cmul(y3,w3);
}

// stages m=4,16,64,256 (+ optional LDS radix-2 tail). Returns result buffer.
template<bool INV, bool DO_TAIL>
__device__ float2* fft2048_mid(float2* src, float2* dst, const float2* tw, int tid)
{
  const float sg = INV ? 1.0f : -1.0f;
  #pragma unroll
  for (int st = 0; st < 4; st++) {
    int m = 4 << (2*st);
    __syncthreads();
    int i = tid;
    int j = i & ~(m-1);
    float2 c0 = src[i];
    float2 c1 = src[i + 512];
    float2 c2 = src[i + 1024];
    float2 c3 = src[i + 1536];
    float2 s02 = cadd(c0,c2), d02 = csub(c0,c2);
    float2 s13 = cadd(c1,c3), d13 = csub(c1,c3);
    float2 jd13 = make_float2(-sg*d13.y, sg*d13.x);
    float2 y0 = cadd(s02,s13);
    float2 y1 = cadd(d02,jd13);
    float2 y2 = csub(s02,s13);
    float2 y3 = csub(d02,jd13);
    float2 w1 = tw[j];
    if (INV) w1.y = -w1.y;
    float2 w2 = cmul(w1,w1);
    float2 w3 = cmul(w2,w1);
    int o = i + 3*j;
    dst[o]       = y0;
    dst[o + m]   = cmul(y1,w1);
    dst[o + 2*m] = cmul(y2,w2);
    dst[o + 3*m] = cmul(y3,w3);
    float2* t2 = src; src = dst; dst = t2;
  }
  if (DO_TAIL) {   // m=1024 radix-2, twiddle = 1
    __syncthreads();
    #pragma unroll
    for (int ii = 0; ii < 2; ii++) {
      int i = tid + ii*512;
      float2 a = src[i], b = src[i + 1024];
      dst[i]        = cadd(a,b);
      dst[i + 1024] = csub(a,b);
    }
    float2* t2 = src; src = dst; dst = t2;
  }
  __syncthreads();
  return src;
}

// ---- Engine B (kfft, latency regime: 1 block/CU): mixed-radix (8..8,4)
// Stockham DIF FFT, padded, T=256.
template<int N, int T, bool INV>
__device__ float2* fft_stockham8(float2* a, float2* b, int tid) {
  float2* src = a; float2* dst = b;
  const float base = (INV ? 6.283185307179586f : -6.283185307179586f) / (float)N;
  const float sg = INV ? 1.0f : -1.0f;
  const float C8 = 0.70710678118654752f;
  int m = 1;
  while (m * 8 <= N) {
    __syncthreads();
    #pragma unroll
    for (int ii = 0; ii < N/8/T; ii++) {
      int i = tid + ii*T;
      int j = i & ~(m-1);
      float2 c[8];
      #pragma unroll
      for (int t = 0; t < 8; t++) c[t] = src[lp(i + t*(N/8))];
      float2 s0=cadd(c[0],c[4]), d0=csub(c[0],c[4]);
      float2 s1=cadd(c[1],c[5]), d1=csub(c[1],c[5]);
      float2 s2=cadd(c[2],c[6]), d2=csub(c[2],c[6]);
      float2 s3=cadd(c[3],c[7]), d3=csub(c[3],c[7]);
      float2 t1 = make_float2(C8*(d1.x - sg*d1.y), C8*(d1.y + sg*d1.x));
      float2 t2 = make_float2(-sg*d2.y, sg*d2.x);
      float2 t3 = make_float2(-C8*(d3.x + sg*d3.y), C8*(sg*d3.x - d3.y));
      float2 es=cadd(s0,s2), ed=csub(s0,s2), fs=cadd(s1,s3), fd=csub(s1,s3);
      float2 je = make_float2(-sg*fd.y, sg*fd.x);
      float2 y0=cadd(es,fs), y4=csub(es,fs);
      float2 y2=cadd(ed,je), y6=csub(ed,je);
      float2 os=cadd(d0,t2), od=csub(d0,t2), ps=cadd(t1,t3), pd=csub(t1,t3);
      float2 jo = make_float2(-sg*pd.y, sg*pd.x);
      float2 y1=cadd(os,ps), y5=csub(os,ps);
      float2 y3=cadd(od,jo), y7=csub(od,jo);
      float ang = base*(float)j;
      float sn, cs; __sincosf(ang, &sn, &cs);
      float2 w1 = make_float2(cs, sn);
      float2 w2 = cmul(w1,w1), w3 = cmul(w2,w1), w4 = cmul(w2,w2);
      float2 w5 = cmul(w4,w1), w6 = cmul(w4,w2), w7 = cmul(w4,w3);
      int o = i + 7*j;
      dst[lp(o)]       = y0;
      dst[lp(o + m)]   = cmul(y1,w1);
      dst[lp(o + 2*m)] = cmul(y2,w2);
      dst[lp(o + 3*m)] = cmul(y3,w3);
      dst[lp(o + 4*m)] = cmul(y4,w4);
      dst[lp(o + 5*m)] = cmul(y5,w5);
      dst[lp(o + 6*m)] = cmul(y6,w6);
      dst[lp(o + 7*m)] = cmul(y7,w7);
    }
    float2* tswap = src; src = dst; dst = tswap;
    m <<= 3;
  }
  if (m * 4 <= N) {   // radix-4 tail
    __syncthreads();
    #pragma unroll
    for (int ii = 0; ii < N/4/T; ii++) {
      int i = tid + ii*T;
      int j = i & ~(m-1);
      float2 c0 = src[lp(i)];
      float2 c1 = src[lp(i + N/4)];
      float2 c2 = src[lp(i + 2*(N/4))];
      float2 c3 = src[lp(i + 3*(N/4))];
      float2 s02 = cadd(c0,c2), d02 = csub(c0,c2);
      float2 s13 = cadd(c1,c3), d13 = csub(c1,c3);
      float2 jd13 = make_float2(-sg*d13.y, sg*d13.x);
      float2 y0 = cadd(s02, s13);
      float2 y1 = cadd(d02, jd13);
      float2 y2 = csub(s02, s13);
      float2 y3 = csub(d02, jd13);
      float ang = base * (float)j;
      float sn, cs; __sincosf(ang, &sn, &cs);
      float2 w1 = make_float2(cs, sn);
      float2 w2 = cmul(w1, w1);
      float2 w3 = cmul(w2, w1);
      int o = i + 3*j;
      dst[lp(o)]       = y0;
      dst[lp(o + m)]   = cmul(y1, w1);
      dst[lp(o + 2*m)] = cmul(y2, w2);
      dst[lp(o + 3*m)] = cmul(y3, w3);
    }
    float2* tswap = src; src = dst; dst = tswap;
    m <<= 2;
  }
  if (m * 2 <= N) {   // radix-2 tail
    __syncthreads();
    #pragma unroll
    for (int ii = 0; ii < N/2/T; ii++) {
      int i = tid + ii*T;
      int j = i & ~(m-1);
      float2 c0 = src[lp(i)], c1 = src[lp(i + N/2)];
      float ang = base * (float)j;
      float sn, cs; __sincosf(ang, &sn, &cs);
      float2 sum = cadd(c0,c1), dif = csub(c0,c1);
      dst[lp(i + j)]     = sum;
      dst[lp(i + j + m)] = cmul(dif, make_float2(cs,sn));
    }
    float2* tswap = src; src = dst; dst = tswap;
    m <<= 1;
  }
  __syncthreads();
  return src;
}

// ---- device bodies for the fused front-end kernel ----

// transpose u (b,t,d) -> ut (b,d,t), 64x64 tile, float4 both global sides,
// 4 outstanding loads/stores per thread (r17: latency hiding). LDS stride 65:
// banks (r + 4c + e) mod 32 both phases -> <=2-way = free (m136).
__device__ void transpose_body64(const float* __restrict__ u, float* __restrict__ ut,
                                 int idx, int tid, float* tile)
{
  int t0 = (idx & 31) * 64;          // 32 t-tiles
  int d0 = ((idx >> 5) & 7) * 64;    // 8 d-tiles
  int b  = idx >> 8;                 // 8 batches
  int r  = tid >> 4;                 // 0..15
  int cb = (tid & 15) * 4;           // 0..60
  #pragma unroll
  for (int it = 0; it < 4; it++) {
    int rr = r + it*16;
    float4 v = *reinterpret_cast<const float4*>(&u[((size_t)b*LS + t0 + rr)*DM + d0 + cb]);
    tile[rr*65 + cb+0] = v.x;
    tile[rr*65 + cb+1] = v.y;
    tile[rr*65 + cb+2] = v.z;
    tile[rr*65 + cb+3] = v.w;
  }
  __syncthreads();
  #pragma unroll
  for (int it = 0; it < 4; it++) {
    int dd = r + it*16;
    float4 o;
    o.x = tile[(cb+0)*65 + dd];
    o.y = tile[(cb+1)*65 + dd];
    o.z = tile[(cb+2)*65 + dd];
    o.w = tile[(cb+3)*65 + dd];
    *reinterpret_cast<float4*>(&ut[((size_t)b*DM + d0 + dd)*LS + t0 + cb]) = o;
  }
}

// Cauchy kernel evaluation at roots of unity -> at (d, 2048)
// 2048 blocks (512 l each). f = -i*g, g = (2/step)*tan(pi*l/L).
// NOTE: g MUST use precise sincosf + IEEE div (native __sincosf -> cos==0 at
// l=1024 -> rcp -> inf -> NaN).
__device__ void cauchy_body(const float* __restrict__ lam_g, const float* __restrict__ p_g,
                            const float* __restrict__ q_g,   const float* __restrict__ B_g,
                            const float* __restrict__ Ct_g,  const float* __restrict__ logstep_g,
                            float2* __restrict__ at, int idx, int tid, float* tabRaw)
{
  float (*tab)[12] = reinterpret_cast<float(*)[12]>(tabRaw);
  int d     = idx & 511;
  int chunk = idx >> 9;   // 0..3
  float tos = 2.0f / expf(logstep_g[d]);
  float invtos = __builtin_amdgcn_rcpf(tos);

  if (tid < NS) {
    int n = tid;
    float lx = lam_g[2*n], ly = lam_g[2*n+1];
    cf pn   = make_float2(p_g[2*n],   p_g[2*n+1]);
    cf qn   = make_float2(q_g[2*n],   q_g[2*n+1]);
    cf Bdn  = make_float2(B_g[(d*NS+n)*2],  B_g[(d*NS+n)*2+1]);
    cf Cdn  = make_float2(Ct_g[(d*NS+n)*2], Ct_g[(d*NS+n)*2+1]);
    cf a0 = cconjf(Cdn);
    cf a1 = cconjf(qn);
    cf w0 = cmul(a0, Bdn);
    cf w1 = cmul(a0, pn);
    cf w2 = cmul(a1, Bdn);
    cf w3 = cmul(a1, pn);
    tab[n][0] = -lx;  tab[n][1] = ly;   tab[n][2] = lx*lx; tab[n][3] = w0.x;
    tab[n][4] = w0.y; tab[n][5] = w1.x; tab[n][6] = w1.y;  tab[n][7] = w2.x;
    tab[n][8] = w2.y; tab[n][9] = w3.x; tab[n][10] = w3.y; tab[n][11] = 0.f;
  }

  float gg[2];
  #pragma unroll
  for (int h = 0; h < 2; h++) {
    int l = chunk*512 + h*256 + tid;
    float half_ang = 3.14159265358979323846f * (float)l / (float)LS;
    float sn, cs;
    sincosf(half_ang, &sn, &cs);         // precise: cs != 0 at l=1024
    gg[h] = tos * (sn / cs);             // tos * tan(pi*l/L)
  }
  float2 g2 = make_float2(gg[0], gg[1]);
  __syncthreads();

  float2 k0x = splat2(0.f), k0y = splat2(0.f);
  float2 k1x = splat2(0.f), k1y = splat2(0.f);
  float2 k2x = splat2(0.f), k2y = splat2(0.f);
  float2 k3x = splat2(0.f), k3y = splat2(0.f);

  #pragma unroll 4
  for (int n = 0; n < NS; n++) {
    float4 t0 = *reinterpret_cast<const float4*>(&tab[n][0]);
    float4 t1 = *reinterpret_cast<const float4*>(&tab[n][4]);
    float4 t2 = *reinterpret_cast<const float4*>(&tab[n][8]);
    float2 e   = f2add(g2, splat2(t0.y));           // g + ly
    float2 mag = f2fma(e, e, splat2(t0.z));         // lx^2 + e^2
    float2 inv = rcp2(mag);
    float2 rx  = f2mul(splat2(t0.x), inv);          // -lx * inv
    float2 ry  = f2mul(e, inv);
    k0x = f2fma(splat2(t0.w), rx, k0x);
    k0x = f2fma(splat2(-t1.x), ry, k0x);
    k0y = f2fma(splat2(t0.w), ry, k0y);
    k0y = f2fma(splat2(t1.x), rx, k0y);
    k1x = f2fma(splat2(t1.y), rx, k1x);
    k1x = f2fma(splat2(-t1.z), ry, k1x);
    k1y = f2fma(splat2(t1.y), ry, k1y);
    k1y = f2fma(splat2(t1.z), rx, k1y);
    k2x = f2fma(splat2(t1.w), rx, k2x);
    k2x = f2fma(splat2(-t2.x), ry, k2x);
    k2y = f2fma(splat2(t1.w), ry, k2y);
    k2y = f2fma(splat2(t2.x), rx, k2y);
    k3x = f2fma(splat2(t2.y), rx, k3x);
    k3x = f2fma(splat2(-t2.z), ry, k3x);
    k3y = f2fma(splat2(t2.y), ry, k3y);
    k3y = f2fma(splat2(t2.z), rx, k3y);
  }

  #pragma unroll
  for (int h = 0; h < 2; h++) {
    int l = chunk*512 + h*256 + tid;
    float gv = (h == 0) ? g2.x : g2.y;
    cf k0 = make_float2(h==0?k0x.x:k0x.y, h==0?k0y.x:k0y.y);
    cf k1 = make_float2(h==0?k1x.x:k1x.y, h==0?k1y.x:k1y.y);
    cf k2 = make_float2(h==0?k2x.x:k2x.y, h==0?k2y.x:k2y.y);
    cf k3 = make_float2(h==0?k3x.x:k3x.y, h==0?k3y.x:k3y.y);
    cf t1c = cdiv_fast(cmul(k1, k2), make_float2(1.0f + k3.x, k3.y));
    cf inner = csub(k0, t1c);
    cf c2 = make_float2(1.0f, -gv * invtos);        // 2/(1+w) = 1 - i*tan
    at[(size_t)d*LS + l] = cmul(c2, inner);
  }
}

// W fp32 -> bf16
__device__ void wb_body(const float* __restrict__ W, ushort* __restrict__ Wb,
                        int idx, int tid)
{
  int i = (idx*256 + tid)*4;
  float4 v = *reinterpret_cast<const float4*>(W + i);
  uint2 o;
  o.x = (uint)f2bf(v.x) | ((uint)f2bf(v.y) << 16);
  o.y = (uint)f2bf(v.z) | ((uint)f2bf(v.w) << 16);
  *reinterpret_cast<uint2*>(Wb + i) = o;
}

// ---- K0 (fused front-end): transpose64 (2048) || cauchy (2048) || wb (256)
// Interleave 1:1 so HBM-bound and VALU-bound waves co-reside (m114).
__global__ __launch_bounds__(256) void fused0_kernel(
    const float* __restrict__ u, float* __restrict__ ut,
    const float* __restrict__ lam_g, const float* __restrict__ p_g,
    const float* __restrict__ q_g,   const float* __restrict__ B_g,
    const float* __restrict__ Ct_g,  const float* __restrict__ logstep_g,
    float2* __restrict__ at,
    const float* __restrict__ W, ushort* __restrict__ Wb)
{
  __shared__ float lds[64*65];   // max(transpose tile 16.6 KB, cauchy tab 3 KB)
  int bid = blockIdx.x;
  int tid = threadIdx.x;
  if (bid < 4096) {
    int g = bid >> 1, r = bid & 1;    // 2048 groups of {1 transpose + 1 cauchy}
    if (r == 0) transpose_body64(u, ut, g, tid, lds);
    else        cauchy_body(lam_g, p_g, q_g, B_g, Ct_g, logstep_g, at, g, tid, lds);
  } else {
    wb_body(W, Wb, bid - 4096, tid);
  }
}

// ---- K1b: at (2 channels) -> Kf SPLIT layout: per channel row of LF float2:
//      [0,LS)  = even bins  Kf[2k]   (= Hermitian part of at, no FFT)
//      [LS,LF) = odd  bins  Kf[2k+1] (one packed FFT2048 + twiddle + FFT2048)
__global__ __launch_bounds__(256) void kfft_kernel(
    const float2* __restrict__ at, float2* __restrict__ Kf)
{
  __shared__ float2 bufA[LSP];
  __shared__ float2 bufB[LSP];
  int tid = threadIdx.x;
  int d0 = blockIdx.x * 2;
  const float2* at0 = at + (size_t)d0*LS;
  const float2* at1 = at0 + LS;
  float2* Kf0 = Kf + (size_t)d0*LF;
  float2* Kf1 = Kf0 + LF;

  #pragma unroll
  for (int s = 0; s < 8; s++) {
    int k = tid + s*256;
    int nk = (LS - k) & (LS - 1);
    cf a0k = at0[k], a0n = at0[nk];
    cf a1k = at1[k], a1n = at1[nk];
    cf H0 = make_float2(0.5f*(a0k.x + a0n.x), 0.5f*(a0k.y - a0n.y));
    cf H1 = make_float2(0.5f*(a1k.x + a1n.x), 0.5f*(a1k.y - a1n.y));
    Kf0[k] = H0;                                       // even bins
    Kf1[k] = H1;
    bufA[lp(k)] = make_float2(H0.x - H1.y, H0.y + H1.x);   // H0 + i*H1
  }
  float2* res = fft_stockham8<LS, 256, true>(bufA, bufB, tid);  // unnorm ifft
  float2* other = (res == bufA) ? bufB : bufA;
  #pragma unroll
  for (int s = 0; s < 8; s++) {
    int t = tid + s*256;
    float ang = 3.14159265358979323846f * (float)t / (float)LS;
    float sn, cs;
    __sincosf(ang, &sn, &cs);
    cf Kc = cscalef(res[lp(t)], 1.0f/(float)LS);  // K0[t] + i*K1[t]
    other[lp(t)] = cmul(Kc, make_float2(cs, -sn)); // * w^t
  }
  float2* G = fft_stockham8<LS, 256, false>(other, res, tid);
  #pragma unroll
  for (int s = 0; s < 4; s++) {
    int k = tid + s*256;        // 0..1023
    int rk = LS - 1 - k;        // 2047-k
    cf Gk = G[lp(k)], Gr = G[lp(rk)];
    cf F0 = make_float2(0.5f*(Gk.x + Gr.x), 0.5f*(Gk.y - Gr.y));
    cf F1 = make_float2(0.5f*(Gk.y + Gr.y), 0.5f*(Gr.x - Gk.x));
    Kf0[LS + k]  = F0;                                 // odd bins
    Kf0[LS + rk] = cconjf(F0);
    Kf1[LS + k]  = F1;
    Kf1[LS + rk] = cconjf(F1);
  }
}

// ---- K2: fused conv per (batch, channel-pair), parity-split (all len-2048).
// Engine A with LDS twiddle table + register-fused first/last stages (r17).
__global__ __launch_bounds__(512) void conv_kernel(
    const float* __restrict__ ut, const float2* __restrict__ Kf,
    const float* __restrict__ Dv, ushort* __restrict__ gb)
{
  __shared__ float2 bufA[LS];
  __shared__ float2 bufB[LS];
  __shared__ float2 twtab[512];    // e^{-2pi i j/2048}, j<512
  int tid = threadIdx.x;
  int d0 = blockIdx.x * 2;
  int b  = blockIdx.y;
  const float* u0p = ut + ((size_t)b*DM + d0)*LS;
  const float* u1p = u0p + LS;
  const float2* Kf0 = Kf + (size_t)d0 * LF;   // [0,LS) even, [LS,LF) odd
  const float2* Kf1 = Kf0 + LF;

  {  // build twiddle table: one sincos per thread (T=512)
    float ang = -6.283185307179586f * (float)tid / (float)LS;
    float sn, cs; __sincosf(ang, &sn, &cs);
    twtab[tid] = make_float2(cs, sn);
  }

  float u0r[4], u1r[4];
  #pragma unroll
  for (int s = 0; s < 4; s++) {
    int t = tid + s*512;
    u0r[s] = u0p[t]; u1r[s] = u1p[t];
  }
  __syncthreads();   // twtab ready (reg_stage1 reads it)

  // ---- even parity: forward (reg stage1 from loads) ----
  reg_stage1<false>(make_float2(u0r[0],u1r[0]), make_float2(u0r[1],u1r[1]),
                    make_float2(u0r[2],u1r[2]), make_float2(u0r[3],u1r[3]),
                    twtab, tid, bufA);
  float2* Z = fft2048_mid<false, true>(bufA, bufB, twtab, tid);   // -> bufB
  float2* other = (Z == bufA) ? bufB : bufA;                      // bufA (dead)
  // spectral multiply even -> regs, then reg inverse stage1 into 'other'
  cf yv[4];
  #pragma unroll
  for (int s = 0; s < 4; s++) {
    int mq = tid + s*512;
    int mm = (LS - mq) & (LS - 1);
    cf Za = Z[mq], Zb = Z[mm];
    cf U0 = make_float2(0.5f*(Za.x + Zb.x), 0.5f*(Za.y - Zb.y));
    cf U1 = make_float2(0.5f*(Za.y + Zb.y), 0.5f*(Zb.x - Za.x));
    cf Y0 = cmul(U0, Kf0[mq]);
    cf Y1 = cmul(U1, Kf1[mq]);
    yv[s] = make_float2(Y0.x - Y1.y, Y0.y + Y1.x);
  }
  reg_stage1<true>(yv[0], yv[1], yv[2], yv[3], twtab, tid, other);
  float2* A5 = fft2048_mid<true, false>(other, Z, twtab, tid);    // -> bufA
  // reg radix-2 tail even
  cf areg[4];
  {
    cf s0 = A5[tid], s1 = A5[tid+512], s2 = A5[tid+1024], s3 = A5[tid+1536];
    areg[0] = cadd(s0,s2); areg[1] = cadd(s1,s3);
    areg[2] = csub(s0,s2); areg[3] = csub(s1,s3);
  }

  // ---- odd parity: stage z = u * e^{-i pi t/L} in regs, reg stage1 ----
  float2* stB = (A5 == bufA) ? bufB : bufA;   // bufB (dead after m=256 read)
  {
    cf z[4];
    #pragma unroll
    for (int s = 0; s < 4; s++) {
      int t = tid + s*512;
      float ang = -3.14159265358979323846f * (float)t / (float)LS;
      float sn, cs; __sincosf(ang, &sn, &cs);
      z[s] = cmul(make_float2(u0r[s], u1r[s]), make_float2(cs, sn));
    }
    reg_stage1<false>(z[0], z[1], z[2], z[3], twtab, tid, stB);
  }
  float2* Z2 = fft2048_mid<false, true>(stB, A5, twtab, tid);     // -> bufA
  float2* other2 = (Z2 == bufA) ? bufB : bufA;                    // bufB
  cf yv2[4];
  #pragma unroll
  for (int s = 0; s < 4; s++) {
    int mq = tid + s*512;
    int mm = LS - 1 - mq;
    cf Za = Z2[mq], Zb = Z2[mm];
    cf U0 = make_float2(0.5f*(Za.x + Zb.x), 0.5f*(Za.y - Zb.y));
    cf U1 = make_float2(0.5f*(Za.y + Zb.y), 0.5f*(Zb.x - Za.x));
    cf Y0 = cmul(U0, Kf0[LS + mq]);
    cf Y1 = cmul(U1, Kf1[LS + mq]);
    yv2[s] = make_float2(Y0.x - Y1.y, Y0.y + Y1.x);
  }
  reg_stage1<true>(yv2[0], yv2[1], yv2[2], yv2[3], twtab, tid, other2);
  float2* C5 = fft2048_mid<true, false>(other2, Z2, twtab, tid);  // -> bufB
  cf creg[4];
  {
    cf s0 = C5[tid], s1 = C5[tid+512], s2 = C5[tid+1024], s3 = C5[tid+1536];
    creg[0] = cadd(s0,s2); creg[1] = cadd(s1,s3);
    creg[2] = csub(s0,s2); creg[3] = csub(s1,s3);
  }

  // ---- epilogue: y[t] = (a + e^{+i pi t/L} c)/LF + D*u -> GELU -> bf16 ----
  float dv0 = Dv[d0], dv1 = Dv[d0+1];
  ushort* g0 = gb + ((size_t)b*DM + d0)*LS;
  ushort* g1 = g0 + LS;
  #pragma unroll
  for (int s = 0; s < 4; s++) {
    int t = tid + s*512;
    float ang = 3.14159265358979323846f * (float)t / (float)LS;
    float sn, cs; __sincosf(ang, &sn, &cs);
    cf bb = cmul(creg[s], make_float2(cs, sn));
    float y0 = (areg[s].x + bb.x) * (1.0f/LF) + dv0 * u0r[s];
    float y1 = (areg[s].y + bb.y) * (1.0f/LF) + dv1 * u1r[s];
    g0[t] = f2bf(gelu_f(y0));
    g1[t] = f2bf(gelu_f(y1));
  }
}

// ---- K3: fused MFMA GEMM + bias + residual + LayerNorm, A-transpose in LDS.
#define ASTRIDE 68
__global__ __launch_bounds__(512) void gemm_ln_kernel(
    const ushort* __restrict__ gb, const ushort* __restrict__ Wbm,
    const float* __restrict__ bias, const float* __restrict__ u,
    const float* __restrict__ gamma, const float* __restrict__ beta,
    float* __restrict__ out)
{
  __shared__ ushort Ast[64*ASTRIDE];  // [d][t], padded
  __shared__ ushort Bs[512*64];       // [n][k], XOR-swizzled by (row&7)
  __shared__ float red[2][64][4];     // {sum,sumsq}[row_local][wn]
  int tid = threadIdx.x;
  int b  = blockIdx.y;
  int t0 = blockIdx.x * 64;
  int wid = tid >> 6, lane = tid & 63;
  int wm = wid >> 2, wn = wid & 3;     // 2 x 4
  int m = lane & 15, q = lane >> 4;

  f32x4 acc[2][8];
  #pragma unroll
  for (int i = 0; i < 2; i++)
    #pragma unroll
    for (int j = 0; j < 8; j++)
      acc[i][j] = (f32x4){0.f, 0.f, 0.f, 0.f};

  for (int k0 = 0; k0 < DM; k0 += 64) {
    {
      int r = tid >> 3, g = tid & 7;
      uint4 va = *reinterpret_cast<const uint4*>(gb + ((size_t)b*DM + k0 + r)*LS + t0 + g*8);
      *reinterpret_cast<uint2*>(&Ast[r*ASTRIDE + g*8])     = make_uint2(va.x, va.y);
      *reinterpret_cast<uint2*>(&Ast[r*ASTRIDE + g*8 + 4]) = make_uint2(va.z, va.w);
    }
    #pragma unroll
    for (int i = 0; i < 8; i++) {
      int idx = tid + i*512;
      int r = idx >> 3, g = idx & 7;
      uint4 vb = *reinterpret_cast<const uint4*>(Wbm + (size_t)r*DM + k0 + g*8);
      *reinterpret_cast<uint4*>(&Bs[r*64 + ((g ^ (r&7))*8)]) = vb;
    }
    __syncthreads();
    #pragma unroll
    for (int kk = 0; kk < 64; kk += 32) {
      int gk = (kk >> 3) + q;
      bf16x8 af[2], bfr[8];
      #pragma unroll
      for (int mi = 0; mi < 2; mi++) {
        int trow = wm*32 + mi*16 + m;
        bf16x8 v;
        #pragma unroll
        for (int e = 0; e < 8; e++)
          v[e] = (short)Ast[(gk*8 + e)*ASTRIDE + trow];
        af[mi] = v;
      }
      #pragma unroll
      for (int ni = 0; ni < 8; ni++) {
        int row = wn*128 + ni*16 + m;
        bfr[ni] = *reinterpret_cast<const bf16x8*>(&Bs[row*64 + ((gk ^ (row&7))*8)]);
      }
      #pragma unroll
      for (int mi = 0; mi < 2; mi++)
        #pragma unroll
        for (int ni = 0; ni < 8; ni++)
          acc[mi][ni] = __builtin_amdgcn_mfma_f32_16x16x32_bf16(af[mi], bfr[ni], acc[mi][ni], 0, 0, 0);
    }
    __syncthreads();
  }

  // ---- epilogue: bias + residual, accumulate row partials ----
  float sum_[2][4], sq_[2][4];
  #pragma unroll
  for (int mi = 0; mi < 2; mi++)
    #pragma unroll
    for (int jj = 0; jj < 4; jj++) { sum_[mi][jj] = 0.f; sq_[mi][jj] = 0.f; }

  #pragma unroll
  for (int mi = 0; mi < 2; mi++) {
    #pragma unroll
    for (int ni = 0; ni < 8; ni++) {
      int col = wn*128 + ni*16 + m;
      float bb = bias[col];
      #pragma unroll
      for (int jj = 0; jj < 4; jj++) {
        int row = t0 + wm*32 + mi*16 + q*4 + jj;
        float y = acc[mi][ni][jj] + bb + u[((size_t)b*LS + row)*DM + col];
        acc[mi][ni][jj] = y;
        sum_[mi][jj] += y;
        sq_[mi][jj]  += y*y;
      }
    }
  }
  #pragma unroll
  for (int mi = 0; mi < 2; mi++)
    #pragma unroll
    for (int jj = 0; jj < 4; jj++) {
      #pragma unroll
      for (int off = 1; off < 16; off <<= 1) {
        sum_[mi][jj] += __shfl_xor(sum_[mi][jj], off, 64);
        sq_[mi][jj]  += __shfl_xor(sq_[mi][jj],  off, 64);
      }
    }
  if (m == 0) {
    #pragma unroll
    for (int mi = 0; mi < 2; mi++)
      #pragma unroll
      for (int jj = 0; jj < 4; jj++) {
        int rowl = wm*32 + mi*16 + q*4 + jj;
        red[0][rowl][wn] = sum_[mi][jj];
        red[1][rowl][wn] = sq_[mi][jj];
      }
  }
  __syncthreads();
  #pragma unroll
  for (int mi = 0; mi < 2; mi++) {
    #pragma unroll
    for (int jj = 0; jj < 4; jj++) {
      int rowl = wm*32 + mi*16 + q*4 + jj;
      float s  = red[0][rowl][0] + red[0][rowl][1] + red[0][rowl][2] + red[0][rowl][3];
      float s2 = red[1][rowl][0] + red[1][rowl][1] + red[1][rowl][2] + red[1][rowl][3];
      float mu  = s * (1.0f/DM);
      float var = s2 * (1.0f/DM) - mu*mu;
      float rs  = rsqrtf(var + 1e-5f);
      int row = t0 + rowl;
      #pragma unroll
      for (int ni = 0; ni < 8; ni++) {
        int col = wn*128 + ni*16 + m;
        size_t off = ((size_t)b*LS + row)*DM + col;
        out[off] = (acc[mi][ni][jj] - mu) * rs * gamma[col] + beta[col];
      }
    }
  }
}

extern "C" void kernel_launch(void* const* d_in, const int* in_sizes, int n_in,
                              void* d_out, int out_size, void* d_ws, size_t ws_size,
                              hipStream_t stream) {
  const float* u       = (const float*)d_in[0];
  const float* lam     = (const float*)d_in[1];
  const float* p       = (const float*)d_in[2];
  const float* q       = (const float*)d_in[3];
  const float* B       = (const float*)d_in[4];
  const float* Ct      = (const float*)d_in[5];
  const float* Dv      = (const float*)d_in[6];
  const float* logstep = (const float*)d_in[7];
  const float* W       = (const float*)d_in[8];
  const float* bias    = (const float*)d_in[9];
  const float* gamma   = (const float*)d_in[10];
  const float* beta    = (const float*)d_in[11];
  float* out = (float*)d_out;

  // ws layout (48 MB) — live-range table (writer -> last reader), no overlap:
  //   Kf  [0,16M)     kfft -> conv
  //   gb  [16M,32M)   conv -> gemm_ln
  //   at  [32M,40M)   fused0 -> kfft
  //   Wbm [40M,40.5M) fused0 -> gemm_ln
  //   ut  = d_out     fused0 -> conv   (dead before gemm_ln writes out)
  char* wsb = (char*)d_ws;
  float2* Kf  = (float2*)wsb;
  ushort* gb  = (ushort*)(wsb + (size_t)16*1024*1024);
  float2* at  = (float2*)(wsb + (size_t)32*1024*1024);
  ushort* Wbm = (ushort*)(wsb + (size_t)40*1024*1024);
  float* ut = (float*)d_out;

  fused0_kernel<<<dim3(4352), 256, 0, stream>>>(u, ut, lam, p, q, B, Ct, logstep, at, W, Wbm);
  kfft_kernel<<<dim3(DM/2), 256, 0, stream>>>(at, Kf);
  conv_kernel<<<dim3(DM/2, NB), 512, 0, stream>>>(ut, Kf, Dv, gb);
  gemm_ln_kernel<<<dim3(LS/64, NB), 512, 0, stream>>>(gb, Wbm, bias, u, gamma, beta, out);
}

// Round 19
// 136.232 us; speedup vs baseline: 1.1087x; 1.1087x over previous
//
#include <hip/hip_runtime.h>
#include <math.h>

#define DM 512
#define NS 64
#define LS 2048
#define NB 8
#define LF 4096
#define LSP (LS + (LS>>5))   // padded LDS length (kfft radix-8 engine only)

typedef float2 cf;
using bf16x8 = __attribute__((ext_vector_type(8))) short;
using f32x4  = __attribute__((ext_vector_type(4))) float;

__device__ __forceinline__ cf cmul(cf a, cf b){ return make_float2(a.x*b.x - a.y*b.y, a.x*b.y + a.y*b.x); }
__device__ __forceinline__ cf cadd(cf a, cf b){ return make_float2(a.x+b.x, a.y+b.y); }
__device__ __forceinline__ cf csub(cf a, cf b){ return make_float2(a.x-b.x, a.y-b.y); }
__device__ __forceinline__ cf cconjf(cf a){ return make_float2(a.x, -a.y); }
__device__ __forceinline__ cf cscalef(cf a, float s){ return make_float2(a.x*s, a.y*s); }
// approximate complex divide via v_rcp (plenty for 0.11 abs threshold)
__device__ __forceinline__ cf cdiv_fast(cf a, cf b){
  float inv = __builtin_amdgcn_rcpf(b.x*b.x + b.y*b.y);
  return make_float2((a.x*b.x + a.y*b.y)*inv, (a.y*b.x - a.x*b.y)*inv);
}

__device__ __forceinline__ float gelu_f(float x){
  return 0.5f*x*(1.0f + erff(x*0.7071067811865475f));
}

__device__ __forceinline__ ushort f2bf(float x){
  uint u = __float_as_uint(x);
  return (ushort)((u + 0x7fffu + ((u>>16)&1u)) >> 16);
}

// LDS pad helper (kfft radix-8 engine only)
__device__ __forceinline__ int lp(int x){ return x + (x >> 5); }

// float2 elementwise helpers
__device__ __forceinline__ float2 f2add(float2 a, float2 b){ return make_float2(a.x+b.x, a.y+b.y); }
__device__ __forceinline__ float2 f2mul(float2 a, float2 b){ return make_float2(a.x*b.x, a.y*b.y); }
__device__ __forceinline__ float2 f2fma(float2 a, float2 b, float2 c){
  return make_float2(fmaf(a.x,b.x,c.x), fmaf(a.y,b.y,c.y));
}
__device__ __forceinline__ float2 splat2(float s){ return make_float2(s,s); }
__device__ __forceinline__ float2 rcp2(float2 a){
  return make_float2(__builtin_amdgcn_rcpf(a.x), __builtin_amdgcn_rcpf(a.y));
}

// ---- Engine A (conv): N=2048, T=512 Stockham with LDS twiddle table.
// r17: stage m=1 in REGISTERS (each thread's 4 held values are exactly one
// butterfly); stages m=4..256 in LDS; radix-2 tail in LDS (forward; natural
// order needed for Hermitian mirror) or REGISTERS (inverse -> epilogue).
// Measured r18: conv 61 -> ~49 us. KEEP.

template<bool INV>
__device__ __forceinline__ void reg_stage1(cf c0, cf c1, cf c2, cf c3,
                                           const float2* tw, int tid, float2* dst)
{
  const float sg = INV ? 1.0f : -1.0f;
  float2 s02 = cadd(c0,c2), d02 = csub(c0,c2);
  float2 s13 = cadd(c1,c3), d13 = csub(c1,c3);
  float2 jd13 = make_float2(-sg*d13.y, sg*d13.x);
  float2 y0 = cadd(s02,s13);
  float2 y1 = cadd(d02,jd13);
  float2 y2 = csub(s02,s13);
  float2 y3 = csub(d02,jd13);
  float2 w1 = tw[tid];               // m=1 -> j=i=tid
  if (INV) w1.y = -w1.y;
  float2 w2 = cmul(w1,w1);
  float2 w3 = cmul(w2,w1);
  int o = 4*tid;
  dst[o]   = y0;
  dst[o+1] = cmul(y1,w1);
  dst[o+2] = cmul(y2,w2);
  dst[o+3] = cmul(y3,w3);
}

// stages m=4,16,64,256 (+ optional LDS radix-2 tail). Returns result buffer.
template<bool INV, bool DO_TAIL>
__device__ float2* fft2048_mid(float2* src, float2* dst, const float2* tw, int tid)
{
  const float sg = INV ? 1.0f : -1.0f;
  #pragma unroll
  for (int st = 0; st < 4; st++) {
    int m = 4 << (2*st);
    __syncthreads();
    int i = tid;
    int j = i & ~(m-1);
    float2 c0 = src[i];
    float2 c1 = src[i + 512];
    float2 c2 = src[i + 1024];
    float2 c3 = src[i + 1536];
    float2 s02 = cadd(c0,c2), d02 = csub(c0,c2);
    float2 s13 = cadd(c1,c3), d13 = csub(c1,c3);
    float2 jd13 = make_float2(-sg*d13.y, sg*d13.x);
    float2 y0 = cadd(s02,s13);
    float2 y1 = cadd(d02,jd13);
    float2 y2 = csub(s02,s13);
    float2 y3 = csub(d02,jd13);
    float2 w1 = tw[j];
    if (INV) w1.y = -w1.y;
    float2 w2 = cmul(w1,w1);
    float2 w3 = cmul(w2,w1);
    int o = i + 3*j;
    dst[o]       = y0;
    dst[o + m]   = cmul(y1,w1);
    dst[o + 2*m] = cmul(y2,w2);
    dst[o + 3*m] = cmul(y3,w3);
    float2* t2 = src; src = dst; dst = t2;
  }
  if (DO_TAIL) {   // m=1024 radix-2, twiddle = 1
    __syncthreads();
    #pragma unroll
    for (int ii = 0; ii < 2; ii++) {
      int i = tid + ii*512;
      float2 a = src[i], b = src[i + 1024];
      dst[i]        = cadd(a,b);
      dst[i + 1024] = csub(a,b);
    }
    float2* t2 = src; src = dst; dst = t2;
  }
  __syncthreads();
  return src;
}

// ---- Engine B (kfft, latency regime: 1 block/CU): mixed-radix (8..8,4)
// Stockham DIF FFT, padded, T=256.
template<int N, int T, bool INV>
__device__ float2* fft_stockham8(float2* a, float2* b, int tid) {
  float2* src = a; float2* dst = b;
  const float base = (INV ? 6.283185307179586f : -6.283185307179586f) / (float)N;
  const float sg = INV ? 1.0f : -1.0f;
  const float C8 = 0.70710678118654752f;
  int m = 1;
  while (m * 8 <= N) {
    __syncthreads();
    #pragma unroll
    for (int ii = 0; ii < N/8/T; ii++) {
      int i = tid + ii*T;
      int j = i & ~(m-1);
      float2 c[8];
      #pragma unroll
      for (int t = 0; t < 8; t++) c[t] = src[lp(i + t*(N/8))];
      float2 s0=cadd(c[0],c[4]), d0=csub(c[0],c[4]);
      float2 s1=cadd(c[1],c[5]), d1=csub(c[1],c[5]);
      float2 s2=cadd(c[2],c[6]), d2=csub(c[2],c[6]);
      float2 s3=cadd(c[3],c[7]), d3=csub(c[3],c[7]);
      float2 t1 = make_float2(C8*(d1.x - sg*d1.y), C8*(d1.y + sg*d1.x));
      float2 t2 = make_float2(-sg*d2.y, sg*d2.x);
      float2 t3 = make_float2(-C8*(d3.x + sg*d3.y), C8*(sg*d3.x - d3.y));
      float2 es=cadd(s0,s2), ed=csub(s0,s2), fs=cadd(s1,s3), fd=csub(s1,s3);
      float2 je = make_float2(-sg*fd.y, sg*fd.x);
      float2 y0=cadd(es,fs), y4=csub(es,fs);
      float2 y2=cadd(ed,je), y6=csub(ed,je);
      float2 os=cadd(d0,t2), od=csub(d0,t2), ps=cadd(t1,t3), pd=csub(t1,t3);
      float2 jo = make_float2(-sg*pd.y, sg*pd.x);
      float2 y1=cadd(os,ps), y5=csub(os,ps);
      float2 y3=cadd(od,jo), y7=csub(od,jo);
      float ang = base*(float)j;
      float sn, cs; __sincosf(ang, &sn, &cs);
      float2 w1 = make_float2(cs, sn);
      float2 w2 = cmul(w1,w1), w3 = cmul(w2,w1), w4 = cmul(w2,w2);
      float2 w5 = cmul(w4,w1), w6 = cmul(w4,w2), w7 = cmul(w4,w3);
      int o = i + 7*j;
      dst[lp(o)]       = y0;
      dst[lp(o + m)]   = cmul(y1,w1);
      dst[lp(o + 2*m)] = cmul(y2,w2);
      dst[lp(o + 3*m)] = cmul(y3,w3);
      dst[lp(o + 4*m)] = cmul(y4,w4);
      dst[lp(o + 5*m)] = cmul(y5,w5);
      dst[lp(o + 6*m)] = cmul(y6,w6);
      dst[lp(o + 7*m)] = cmul(y7,w7);
    }
    float2* tswap = src; src = dst; dst = tswap;
    m <<= 3;
  }
  if (m * 4 <= N) {   // radix-4 tail
    __syncthreads();
    #pragma unroll
    for (int ii = 0; ii < N/4/T; ii++) {
      int i = tid + ii*T;
      int j = i & ~(m-1);
      float2 c0 = src[lp(i)];
      float2 c1 = src[lp(i + N/4)];
      float2 c2 = src[lp(i + 2*(N/4))];
      float2 c3 = src[lp(i + 3*(N/4))];
      float2 s02 = cadd(c0,c2), d02 = csub(c0,c2);
      float2 s13 = cadd(c1,c3), d13 = csub(c1,c3);
      float2 jd13 = make_float2(-sg*d13.y, sg*d13.x);
      float2 y0 = cadd(s02, s13);
      float2 y1 = cadd(d02, jd13);
      float2 y2 = csub(s02, s13);
      float2 y3 = csub(d02, jd13);
      float ang = base * (float)j;
      float sn, cs; __sincosf(ang, &sn, &cs);
      float2 w1 = make_float2(cs, sn);
      float2 w2 = cmul(w1, w1);
      float2 w3 = cmul(w2, w1);
      int o = i + 3*j;
      dst[lp(o)]       = y0;
      dst[lp(o + m)]   = cmul(y1, w1);
      dst[lp(o + 2*m)] = cmul(y2, w2);
      dst[lp(o + 3*m)] = cmul(y3, w3);
    }
    float2* tswap = src; src = dst; dst = tswap;
    m <<= 2;
  }
  if (m * 2 <= N) {   // radix-2 tail
    __syncthreads();
    #pragma unroll
    for (int ii = 0; ii < N/2/T; ii++) {
      int i = tid + ii*T;
      int j = i & ~(m-1);
      float2 c0 = src[lp(i)], c1 = src[lp(i + N/2)];
      float ang = base * (float)j;
      float sn, cs; __sincosf(ang, &sn, &cs);
      float2 sum = cadd(c0,c1), dif = csub(c0,c1);
      dst[lp(i + j)]     = sum;
      dst[lp(i + j + m)] = cmul(dif, make_float2(cs,sn));
    }
    float2* tswap = src; src = dst; dst = tswap;
    m <<= 1;
  }
  __syncthreads();
  return src;
}

// ---- device bodies for the fused front-end kernel ----

// transpose u (b,t,d) -> ut (b,d,t), 32x32 tile, float4 BOTH global sides.
// r18 post-mortem: the 64x64 variant (16.9 KB LDS, 16 strided ds_reads) took
// fused0 43 -> 69 us. REVERTED to this r16 version (measured-good).
__device__ void transpose_body(const float* __restrict__ u, float* __restrict__ ut,
                               int idx, int tid, float* tile)
{
  int t0 = (idx & 63) * 32;          // 64 t-tiles
  int d0 = ((idx >> 6) & 15) * 32;   // 16 d-tiles
  int b  = idx >> 10;                // 8 batches
  int r  = tid >> 3;                 // 0..31 (t within tile)
  int cb = (tid & 7) * 4;            // 0..28 (d within tile)
  float4 v = *reinterpret_cast<const float4*>(&u[((size_t)b*LS + t0 + r)*DM + d0 + cb]);
  tile[r*33 + cb+0] = v.x;
  tile[r*33 + cb+1] = v.y;
  tile[r*33 + cb+2] = v.z;
  tile[r*33 + cb+3] = v.w;
  __syncthreads();
  int d  = tid >> 3;                 // 0..31 (d within tile)
  int tb = (tid & 7) * 4;            // 0..28 (t within tile)
  float4 o;
  o.x = tile[(tb+0)*33 + d];
  o.y = tile[(tb+1)*33 + d];
  o.z = tile[(tb+2)*33 + d];
  o.w = tile[(tb+3)*33 + d];
  *reinterpret_cast<float4*>(&ut[((size_t)b*DM + d0 + d)*LS + t0 + tb]) = o;
}

// Cauchy kernel evaluation at roots of unity -> at (d, 2048)
// 2048 blocks (512 l each). f = -i*g, g = (2/step)*tan(pi*l/L).
// NOTE: g MUST use precise sincosf + IEEE div (native __sincosf -> cos==0 at
// l=1024 -> rcp -> inf -> NaN).
__device__ void cauchy_body(const float* __restrict__ lam_g, const float* __restrict__ p_g,
                            const float* __restrict__ q_g,   const float* __restrict__ B_g,
                            const float* __restrict__ Ct_g,  const float* __restrict__ logstep_g,
                            float2* __restrict__ at, int idx, int tid, float* tabRaw)
{
  float (*tab)[12] = reinterpret_cast<float(*)[12]>(tabRaw);
  int d     = idx & 511;
  int chunk = idx >> 9;   // 0..3
  float tos = 2.0f / expf(logstep_g[d]);
  float invtos = __builtin_amdgcn_rcpf(tos);

  if (tid < NS) {
    int n = tid;
    float lx = lam_g[2*n], ly = lam_g[2*n+1];
    cf pn   = make_float2(p_g[2*n],   p_g[2*n+1]);
    cf qn   = make_float2(q_g[2*n],   q_g[2*n+1]);
    cf Bdn  = make_float2(B_g[(d*NS+n)*2],  B_g[(d*NS+n)*2+1]);
    cf Cdn  = make_float2(Ct_g[(d*NS+n)*2], Ct_g[(d*NS+n)*2+1]);
    cf a0 = cconjf(Cdn);
    cf a1 = cconjf(qn);
    cf w0 = cmul(a0, Bdn);
    cf w1 = cmul(a0, pn);
    cf w2 = cmul(a1, Bdn);
    cf w3 = cmul(a1, pn);
    tab[n][0] = -lx;  tab[n][1] = ly;   tab[n][2] = lx*lx; tab[n][3] = w0.x;
    tab[n][4] = w0.y; tab[n][5] = w1.x; tab[n][6] = w1.y;  tab[n][7] = w2.x;
    tab[n][8] = w2.y; tab[n][9] = w3.x; tab[n][10] = w3.y; tab[n][11] = 0.f;
  }

  float gg[2];
  #pragma unroll
  for (int h = 0; h < 2; h++) {
    int l = chunk*512 + h*256 + tid;
    float half_ang = 3.14159265358979323846f * (float)l / (float)LS;
    float sn, cs;
    sincosf(half_ang, &sn, &cs);         // precise: cs != 0 at l=1024
    gg[h] = tos * (sn / cs);             // tos * tan(pi*l/L)
  }
  float2 g2 = make_float2(gg[0], gg[1]);
  __syncthreads();

  float2 k0x = splat2(0.f), k0y = splat2(0.f);
  float2 k1x = splat2(0.f), k1y = splat2(0.f);
  float2 k2x = splat2(0.f), k2y = splat2(0.f);
  float2 k3x = splat2(0.f), k3y = splat2(0.f);

  #pragma unroll 4
  for (int n = 0; n < NS; n++) {
    float4 t0 = *reinterpret_cast<const float4*>(&tab[n][0]);
    float4 t1 = *reinterpret_cast<const float4*>(&tab[n][4]);
    float4 t2 = *reinterpret_cast<const float4*>(&tab[n][8]);
    float2 e   = f2add(g2, splat2(t0.y));           // g + ly
    float2 mag = f2fma(e, e, splat2(t0.z));         // lx^2 + e^2
    float2 inv = rcp2(mag);
    float2 rx  = f2mul(splat2(t0.x), inv);          // -lx * inv
    float2 ry  = f2mul(e, inv);
    k0x = f2fma(splat2(t0.w), rx, k0x);
    k0x = f2fma(splat2(-t1.x), ry, k0x);
    k0y = f2fma(splat2(t0.w), ry, k0y);
    k0y = f2fma(splat2(t1.x), rx, k0y);
    k1x = f2fma(splat2(t1.y), rx, k1x);
    k1x = f2fma(splat2(-t1.z), ry, k1x);
    k1y = f2fma(splat2(t1.y), ry, k1y);
    k1y = f2fma(splat2(t1.z), rx, k1y);
    k2x = f2fma(splat2(t1.w), rx, k2x);
    k2x = f2fma(splat2(-t2.x), ry, k2x);
    k2y = f2fma(splat2(t1.w), ry, k2y);
    k2y = f2fma(splat2(t2.x), rx, k2y);
    k3x = f2fma(splat2(t2.y), rx, k3x);
    k3x = f2fma(splat2(-t2.z), ry, k3x);
    k3y = f2fma(splat2(t2.y), ry, k3y);
    k3y = f2fma(splat2(t2.z), rx, k3y);
  }

  #pragma unroll
  for (int h = 0; h < 2; h++) {
    int l = chunk*512 + h*256 + tid;
    float gv = (h == 0) ? g2.x : g2.y;
    cf k0 = make_float2(h==0?k0x.x:k0x.y, h==0?k0y.x:k0y.y);
    cf k1 = make_float2(h==0?k1x.x:k1x.y, h==0?k1y.x:k1y.y);
    cf k2 = make_float2(h==0?k2x.x:k2x.y, h==0?k2y.x:k2y.y);
    cf k3 = make_float2(h==0?k3x.x:k3x.y, h==0?k3y.x:k3y.y);
    cf t1c = cdiv_fast(cmul(k1, k2), make_float2(1.0f + k3.x, k3.y));
    cf inner = csub(k0, t1c);
    cf c2 = make_float2(1.0f, -gv * invtos);        // 2/(1+w) = 1 - i*tan
    at[(size_t)d*LS + l] = cmul(c2, inner);
  }
}

// W fp32 -> bf16
__device__ void wb_body(const float* __restrict__ W, ushort* __restrict__ Wb,
                        int idx, int tid)
{
  int i = (idx*256 + tid)*4;
  float4 v = *reinterpret_cast<const float4*>(W + i);
  uint2 o;
  o.x = (uint)f2bf(v.x) | ((uint)f2bf(v.y) << 16);
  o.y = (uint)f2bf(v.z) | ((uint)f2bf(v.w) << 16);
  *reinterpret_cast<uint2*>(Wb + i) = o;
}

// ---- K0 (fused front-end): transpose (8192) || cauchy (2048) || wb (256)
// Interleave 4:1 so HBM-bound and VALU-bound waves co-reside (m114).
__global__ __launch_bounds__(256) void fused0_kernel(
    const float* __restrict__ u, float* __restrict__ ut,
    const float* __restrict__ lam_g, const float* __restrict__ p_g,
    const float* __restrict__ q_g,   const float* __restrict__ B_g,
    const float* __restrict__ Ct_g,  const float* __restrict__ logstep_g,
    float2* __restrict__ at,
    const float* __restrict__ W, ushort* __restrict__ Wb)
{
  __shared__ float lds[32*33];   // max(transpose tile 4.2 KB, cauchy tab 3 KB)
  int bid = blockIdx.x;
  int tid = threadIdx.x;
  if (bid < 10240) {
    int g = bid / 5, r = bid % 5;     // 2048 groups of {4 transpose + 1 cauchy}
    if (r < 4) transpose_body(u, ut, g*4 + r, tid, lds);
    else       cauchy_body(lam_g, p_g, q_g, B_g, Ct_g, logstep_g, at, g, tid, lds);
  } else {
    wb_body(W, Wb, bid - 10240, tid);
  }
}

// ---- K1b: at (2 channels) -> Kf SPLIT layout: per channel row of LF float2:
//      [0,LS)  = even bins  Kf[2k]   (= Hermitian part of at, no FFT)
//      [LS,LF) = odd  bins  Kf[2k+1] (one packed FFT2048 + twiddle + FFT2048)
__global__ __launch_bounds__(256) void kfft_kernel(
    const float2* __restrict__ at, float2* __restrict__ Kf)
{
  __shared__ float2 bufA[LSP];
  __shared__ float2 bufB[LSP];
  int tid = threadIdx.x;
  int d0 = blockIdx.x * 2;
  const float2* at0 = at + (size_t)d0*LS;
  const float2* at1 = at0 + LS;
  float2* Kf0 = Kf + (size_t)d0*LF;
  float2* Kf1 = Kf0 + LF;

  #pragma unroll
  for (int s = 0; s < 8; s++) {
    int k = tid + s*256;
    int nk = (LS - k) & (LS - 1);
    cf a0k = at0[k], a0n = at0[nk];
    cf a1k = at1[k], a1n = at1[nk];
    cf H0 = make_float2(0.5f*(a0k.x + a0n.x), 0.5f*(a0k.y - a0n.y));
    cf H1 = make_float2(0.5f*(a1k.x + a1n.x), 0.5f*(a1k.y - a1n.y));
    Kf0[k] = H0;                                       // even bins
    Kf1[k] = H1;
    bufA[lp(k)] = make_float2(H0.x - H1.y, H0.y + H1.x);   // H0 + i*H1
  }
  float2* res = fft_stockham8<LS, 256, true>(bufA, bufB, tid);  // unnorm ifft
  float2* other = (res == bufA) ? bufB : bufA;
  #pragma unroll
  for (int s = 0; s < 8; s++) {
    int t = tid + s*256;
    float ang = 3.14159265358979323846f * (float)t / (float)LS;
    float sn, cs;
    __sincosf(ang, &sn, &cs);
    cf Kc = cscalef(res[lp(t)], 1.0f/(float)LS);  // K0[t] + i*K1[t]
    other[lp(t)] = cmul(Kc, make_float2(cs, -sn)); // * w^t
  }
  float2* G = fft_stockham8<LS, 256, false>(other, res, tid);
  #pragma unroll
  for (int s = 0; s < 4; s++) {
    int k = tid + s*256;        // 0..1023
    int rk = LS - 1 - k;        // 2047-k
    cf Gk = G[lp(k)], Gr = G[lp(rk)];
    cf F0 = make_float2(0.5f*(Gk.x + Gr.x), 0.5f*(Gk.y - Gr.y));
    cf F1 = make_float2(0.5f*(Gk.y + Gr.y), 0.5f*(Gr.x - Gk.x));
    Kf0[LS + k]  = F0;                                 // odd bins
    Kf0[LS + rk] = cconjf(F0);
    Kf1[LS + k]  = F1;
    Kf1[LS + rk] = cconjf(F1);
  }
}

// ---- K2: fused conv per (batch, channel-pair), parity-split (all len-2048).
// Engine A with LDS twiddle table + register-fused first/last stages (r17).
__global__ __launch_bounds__(512) void conv_kernel(
    const float* __restrict__ ut, const float2* __restrict__ Kf,
    const float* __restrict__ Dv, ushort* __restrict__ gb)
{
  __shared__ float2 bufA[LS];
  __shared__ float2 bufB[LS];
  __shared__ float2 twtab[512];    // e^{-2pi i j/2048}, j<512
  int tid = threadIdx.x;
  int d0 = blockIdx.x * 2;
  int b  = blockIdx.y;
  const float* u0p = ut + ((size_t)b*DM + d0)*LS;
  const float* u1p = u0p + LS;
  const float2* Kf0 = Kf + (size_t)d0 * LF;   // [0,LS) even, [LS,LF) odd
  const float2* Kf1 = Kf0 + LF;

  {  // build twiddle table: one sincos per thread (T=512)
    float ang = -6.283185307179586f * (float)tid / (float)LS;
    float sn, cs; __sincosf(ang, &sn, &cs);
    twtab[tid] = make_float2(cs, sn);
  }

  float u0r[4], u1r[4];
  #pragma unroll
  for (int s = 0; s < 4; s++) {
    int t = tid + s*512;
    u0r[s] = u0p[t]; u1r[s] = u1p[t];
  }
  __syncthreads();   // twtab ready (reg_stage1 reads it)

  // ---- even parity: forward (reg stage1 from loads) ----
  reg_stage1<false>(make_float2(u0r[0],u1r[0]), make_float2(u0r[1],u1r[1]),
                    make_float2(u0r[2],u1r[2]), make_float2(u0r[3],u1r[3]),
                    twtab, tid, bufA);
  float2* Z = fft2048_mid<false, true>(bufA, bufB, twtab, tid);   // -> bufB
  float2* other = (Z == bufA) ? bufB : bufA;                      // bufA (dead)
  cf yv[4];
  #pragma unroll
  for (int s = 0; s < 4; s++) {
    int mq = tid + s*512;
    int mm = (LS - mq) & (LS - 1);
    cf Za = Z[mq], Zb = Z[mm];
    cf U0 = make_float2(0.5f*(Za.x + Zb.x), 0.5f*(Za.y - Zb.y));
    cf U1 = make_float2(0.5f*(Za.y + Zb.y), 0.5f*(Zb.x - Za.x));
    cf Y0 = cmul(U0, Kf0[mq]);
    cf Y1 = cmul(U1, Kf1[mq]);
    yv[s] = make_float2(Y0.x - Y1.y, Y0.y + Y1.x);
  }
  reg_stage1<true>(yv[0], yv[1], yv[2], yv[3], twtab, tid, other);
  float2* A5 = fft2048_mid<true, false>(other, Z, twtab, tid);
  cf areg[4];
  {
    cf s0 = A5[tid], s1 = A5[tid+512], s2 = A5[tid+1024], s3 = A5[tid+1536];
    areg[0] = cadd(s0,s2); areg[1] = cadd(s1,s3);
    areg[2] = csub(s0,s2); areg[3] = csub(s1,s3);
  }

  // ---- odd parity: stage z = u * e^{-i pi t/L} in regs, reg stage1 ----
  float2* stB = (A5 == bufA) ? bufB : bufA;
  {
    cf z[4];
    #pragma unroll
    for (int s = 0; s < 4; s++) {
      int t = tid + s*512;
      float ang = -3.14159265358979323846f * (float)t / (float)LS;
      float sn, cs; __sincosf(ang, &sn, &cs);
      z[s] = cmul(make_float2(u0r[s], u1r[s]), make_float2(cs, sn));
    }
    reg_stage1<false>(z[0], z[1], z[2], z[3], twtab, tid, stB);
  }
  float2* Z2 = fft2048_mid<false, true>(stB, A5, twtab, tid);
  float2* other2 = (Z2 == bufA) ? bufB : bufA;
  cf yv2[4];
  #pragma unroll
  for (int s = 0; s < 4; s++) {
    int mq = tid + s*512;
    int mm = LS - 1 - mq;
    cf Za = Z2[mq], Zb = Z2[mm];
    cf U0 = make_float2(0.5f*(Za.x + Zb.x), 0.5f*(Za.y - Zb.y));
    cf U1 = make_float2(0.5f*(Za.y + Zb.y), 0.5f*(Zb.x - Za.x));
    cf Y0 = cmul(U0, Kf0[LS + mq]);
    cf Y1 = cmul(U1, Kf1[LS + mq]);
    yv2[s] = make_float2(Y0.x - Y1.y, Y0.y + Y1.x);
  }
  reg_stage1<true>(yv2[0], yv2[1], yv2[2], yv2[3], twtab, tid, other2);
  float2* C5 = fft2048_mid<true, false>(other2, Z2, twtab, tid);
  cf creg[4];
  {
    cf s0 = C5[tid], s1 = C5[tid+512], s2 = C5[tid+1024], s3 = C5[tid+1536];
    creg[0] = cadd(s0,s2); creg[1] = cadd(s1,s3);
    creg[2] = csub(s0,s2); creg[3] = csub(s1,s3);
  }

  // ---- epilogue: y[t] = (a + e^{+i pi t/L} c)/LF + D*u -> GELU -> bf16 ----
  float dv0 = Dv[d0], dv1 = Dv[d0+1];
  ushort* g0 = gb + ((size_t)b*DM + d0)*LS;
  ushort* g1 = g0 + LS;
  #pragma unroll
  for (int s = 0; s < 4; s++) {
    int t = tid + s*512;
    float ang = 3.14159265358979323846f * (float)t / (float)LS;
    float sn, cs; __sincosf(ang, &sn, &cs);
    cf bb = cmul(creg[s], make_float2(cs, sn));
    float y0 = (areg[s].x + bb.x) * (1.0f/LF) + dv0 * u0r[s];
    float y1 = (areg[s].y + bb.y) * (1.0f/LF) + dv1 * u1r[s];
    g0[t] = f2bf(gelu_f(y0));
    g1[t] = f2bf(gelu_f(y1));
  }
}

// ---- K3: fused MFMA GEMM + bias + residual + LayerNorm, A-transpose in LDS.
#define ASTRIDE 68
__global__ __launch_bounds__(512) void gemm_ln_kernel(
    const ushort* __restrict__ gb, const ushort* __restrict__ Wbm,
    const float* __restrict__ bias, const float* __restrict__ u,
    const float* __restrict__ gamma, const float* __restrict__ beta,
    float* __restrict__ out)
{
  __shared__ ushort Ast[64*ASTRIDE];  // [d][t], padded
  __shared__ ushort Bs[512*64];       // [n][k], XOR-swizzled by (row&7)
  __shared__ float red[2][64][4];     // {sum,sumsq}[row_local][wn]
  int tid = threadIdx.x;
  int b  = blockIdx.y;
  int t0 = blockIdx.x * 64;
  int wid = tid >> 6, lane = tid & 63;
  int wm = wid >> 2, wn = wid & 3;     // 2 x 4
  int m = lane & 15, q = lane >> 4;

  f32x4 acc[2][8];
  #pragma unroll
  for (int i = 0; i < 2; i++)
    #pragma unroll
    for (int j = 0; j < 8; j++)
      acc[i][j] = (f32x4){0.f, 0.f, 0.f, 0.f};

  for (int k0 = 0; k0 < DM; k0 += 64) {
    {
      int r = tid >> 3, g = tid & 7;
      uint4 va = *reinterpret_cast<const uint4*>(gb + ((size_t)b*DM + k0 + r)*LS + t0 + g*8);
      *reinterpret_cast<uint2*>(&Ast[r*ASTRIDE + g*8])     = make_uint2(va.x, va.y);
      *reinterpret_cast<uint2*>(&Ast[r*ASTRIDE + g*8 + 4]) = make_uint2(va.z, va.w);
    }
    #pragma unroll
    for (int i = 0; i < 8; i++) {
      int idx = tid + i*512;
      int r = idx >> 3, g = idx & 7;
      uint4 vb = *reinterpret_cast<const uint4*>(Wbm + (size_t)r*DM + k0 + g*8);
      *reinterpret_cast<uint4*>(&Bs[r*64 + ((g ^ (r&7))*8)]) = vb;
    }
    __syncthreads();
    #pragma unroll
    for (int kk = 0; kk < 64; kk += 32) {
      int gk = (kk >> 3) + q;
      bf16x8 af[2], bfr[8];
      #pragma unroll
      for (int mi = 0; mi < 2; mi++) {
        int trow = wm*32 + mi*16 + m;
        bf16x8 v;
        #pragma unroll
        for (int e = 0; e < 8; e++)
          v[e] = (short)Ast[(gk*8 + e)*ASTRIDE + trow];
        af[mi] = v;
      }
      #pragma unroll
      for (int ni = 0; ni < 8; ni++) {
        int row = wn*128 + ni*16 + m;
        bfr[ni] = *reinterpret_cast<const bf16x8*>(&Bs[row*64 + ((gk ^ (row&7))*8)]);
      }
      #pragma unroll
      for (int mi = 0; mi < 2; mi++)
        #pragma unroll
        for (int ni = 0; ni < 8; ni++)
          acc[mi][ni] = __builtin_amdgcn_mfma_f32_16x16x32_bf16(af[mi], bfr[ni], acc[mi][ni], 0, 0, 0);
    }
    __syncthreads();
  }

  // ---- epilogue: bias + residual, accumulate row partials ----
  float sum_[2][4], sq_[2][4];
  #pragma unroll
  for (int mi = 0; mi < 2; mi++)
    #pragma unroll
    for (int jj = 0; jj < 4; jj++) { sum_[mi][jj] = 0.f; sq_[mi][jj] = 0.f; }

  #pragma unroll
  for (int mi = 0; mi < 2; mi++) {
    #pragma unroll
    for (int ni = 0; ni < 8; ni++) {
      int col = wn*128 + ni*16 + m;
      float bb = bias[col];
      #pragma unroll
      for (int jj = 0; jj < 4; jj++) {
        int row = t0 + wm*32 + mi*16 + q*4 + jj;
        float y = acc[mi][ni][jj] + bb + u[((size_t)b*LS + row)*DM + col];
        acc[mi][ni][jj] = y;
        sum_[mi][jj] += y;
        sq_[mi][jj]  += y*y;
      }
    }
  }
  #pragma unroll
  for (int mi = 0; mi < 2; mi++)
    #pragma unroll
    for (int jj = 0; jj < 4; jj++) {
      #pragma unroll
      for (int off = 1; off < 16; off <<= 1) {
        sum_[mi][jj] += __shfl_xor(sum_[mi][jj], off, 64);
        sq_[mi][jj]  += __shfl_xor(sq_[mi][jj],  off, 64);
      }
    }
  if (m == 0) {
    #pragma unroll
    for (int mi = 0; mi < 2; mi++)
      #pragma unroll
      for (int jj = 0; jj < 4; jj++) {
        int rowl = wm*32 + mi*16 + q*4 + jj;
        red[0][rowl][wn] = sum_[mi][jj];
        red[1][rowl][wn] = sq_[mi][jj];
      }
  }
  __syncthreads();
  #pragma unroll
  for (int mi = 0; mi < 2; mi++) {
    #pragma unroll
    for (int jj = 0; jj < 4; jj++) {
      int rowl = wm*32 + mi*16 + q*4 + jj;
      float s  = red[0][rowl][0] + red[0][rowl][1] + red[0][rowl][2] + red[0][rowl][3];
      float s2 = red[1][rowl][0] + red[1][rowl][1] + red[1][rowl][2] + red[1][rowl][3];
      float mu  = s * (1.0f/DM);
      float var = s2 * (1.0f/DM) - mu*mu;
      float rs  = rsqrtf(var + 1e-5f);
      int row = t0 + rowl;
      #pragma unroll
      for (int ni = 0; ni < 8; ni++) {
        int col = wn*128 + ni*16 + m;
        size_t off = ((size_t)b*LS + row)*DM + col;
        out[off] = (acc[mi][ni][jj] - mu) * rs * gamma[col] + beta[col];
      }
    }
  }
}

extern "C" void kernel_launch(void* const* d_in, const int* in_sizes, int n_in,
                              void* d_out, int out_size, void* d_ws, size_t ws_size,
                              hipStream_t stream) {
  const float* u       = (const float*)d_in[0];
  const float* lam     = (const float*)d_in[1];
  const float* p       = (const float*)d_in[2];
  const float* q       = (const float*)d_in[3];
  const float* B       = (const float*)d_in[4];
  const float* Ct      = (const float*)d_in[5];
  const float* Dv      = (const float*)d_in[6];
  const float* logstep = (const float*)d_in[7];
  const float* W       = (const float*)d_in[8];
  const float* bias    = (const float*)d_in[9];
  const float* gamma   = (const float*)d_in[10];
  const float* beta    = (const float*)d_in[11];
  float* out = (float*)d_out;

  // ws layout (48 MB) — live-range table (writer -> last reader), no overlap:
  //   Kf  [0,16M)     kfft -> conv
  //   gb  [16M,32M)   conv -> gemm_ln
  //   at  [32M,40M)   fused0 -> kfft
  //   Wbm [40M,40.5M) fused0 -> gemm_ln
  //   ut  = d_out     fused0 -> conv   (dead before gemm_ln writes out)
  char* wsb = (char*)d_ws;
  float2* Kf  = (float2*)wsb;
  ushort* gb  = (ushort*)(wsb + (size_t)16*1024*1024);
  float2* at  = (float2*)(wsb + (size_t)32*1024*1024);
  ushort* Wbm = (ushort*)(wsb + (size_t)40*1024*1024);
  float* ut = (float*)d_out;

  fused0_kernel<<<dim3(10496), 256, 0, stream>>>(u, ut, lam, p, q, B, Ct, logstep, at, W, Wbm);
  kfft_kernel<<<dim3(DM/2), 256, 0, stream>>>(at, Kf);
  conv_kernel<<<dim3(DM/2, NB), 512, 0, stream>>>(ut, Kf, Dv, gb);
  gemm_ln_kernel<<<dim3(LS/64, NB), 512, 0, stream>>>(gb, Wbm, bias, u, gamma, beta, out);
}